// Round 3
// baseline (4596.006 us; speedup 1.0000x reference)
//
#include <hip/hip_runtime.h>
#include <hip/hip_bf16.h>
#include <cstddef>

// ResCapsNet forward, round 3. conv3_k restructured: 4 chunks x 8 o1-channels,
// 9 barriers/block instead of 64 (round-2 conv3 was 21% VALUBusy, latency-bound
// on 64 barriers). Everything else identical to round 2 (passed, absmax 9.8e-4).
//
// ws layout (fp32-H mode, needs 223,283,200 B; bf16-H fallback if smaller):
//   X    @ 0          26,214,400 fl   raw conv outputs; post-trunk: u_hat overlay
//   H    @ 26,214,400 26,214,400 fl   running activation
//   tail: WT | PART | SB | P | BLOG | S | V  (3,392,000 fl)

#define B_ 128
#define HW_ 80
#define PIX 6400
#define CHW 204800
#define NPRIM 1296

// ---- H storage helpers (fp32 or bf16) ----
__device__ inline float ldH(const float* p, size_t i) { return p[i]; }
__device__ inline float ldH(const unsigned short* p, size_t i) {
  union { unsigned int u; float f; } c; c.u = ((unsigned int)p[i]) << 16; return c.f;
}
__device__ inline void stH(float* p, size_t i, float v) { p[i] = v; }
__device__ inline void stH(unsigned short* p, size_t i, float v) {
  __hip_bfloat16 b = __float2bfloat16(v);
  p[i] = *reinterpret_cast<unsigned short*>(&b);
}

// ---------------- conv1: 1->32, k3 s1 p1, + bias -> X raw ----------------
__global__ __launch_bounds__(256) void conv1_k(const float* __restrict__ x,
                                               const float* __restrict__ w,
                                               const float* __restrict__ bias,
                                               float* __restrict__ out) {
  int idx = blockIdx.x * 256 + threadIdx.x;      // 819200
  int b = idx / PIX, p = idx - b * PIX;
  int y = p / HW_, xx = p - y * HW_;
  const float* xb = x + (size_t)b * PIX;
  float in[3][3];
#pragma unroll
  for (int dy = 0; dy < 3; dy++) {
    int yy = y + dy - 1;
#pragma unroll
    for (int dx = 0; dx < 3; dx++) {
      int xc = xx + dx - 1;
      in[dy][dx] = (yy >= 0 && yy < HW_ && xc >= 0 && xc < HW_) ? xb[yy * HW_ + xc] : 0.f;
    }
  }
  size_t obase = (size_t)b * CHW + p;
#pragma unroll 1
  for (int co = 0; co < 32; co++) {
    float a = bias[co];
#pragma unroll
    for (int t = 0; t < 9; t++) a = fmaf(in[t / 3][t % 3], w[co * 9 + t], a);
    out[obase + (size_t)co * PIX] = a;
  }
}

// ---------------- BN stats over fp32 X ----------------
__global__ __launch_bounds__(256) void stats_part_k(const float* __restrict__ src,
                                                    float* __restrict__ part) {
  int ch = blockIdx.y;
  int p = blockIdx.x * 256 + threadIdx.x;        // 25*256 = 6400
  const float* sp = src + (size_t)ch * PIX + p;
  float s = 0.f, s2 = 0.f;
#pragma unroll 4
  for (int b = 0; b < B_; b++) {
    float v = sp[(size_t)b * CHW];
    s += v; s2 += v * v;
  }
  __shared__ float r1[256], r2[256];
  r1[threadIdx.x] = s; r2[threadIdx.x] = s2;
  __syncthreads();
  for (int st = 128; st > 0; st >>= 1) {
    if (threadIdx.x < st) { r1[threadIdx.x] += r1[threadIdx.x + st]; r2[threadIdx.x] += r2[threadIdx.x + st]; }
    __syncthreads();
  }
  if (threadIdx.x == 0) {
    part[ch * 50 + blockIdx.x * 2 + 0] = r1[0];
    part[ch * 50 + blockIdx.x * 2 + 1] = r2[0];
  }
}

__global__ __launch_bounds__(64) void stats_fin_k(const float* __restrict__ part,
                                                  const float* __restrict__ g,
                                                  const float* __restrict__ bb,
                                                  float* __restrict__ sb) {
  int ch = threadIdx.x;
  if (ch < 32) {
    float s = 0.f, s2 = 0.f;
    for (int j = 0; j < 25; j++) { s += part[ch * 50 + j * 2]; s2 += part[ch * 50 + j * 2 + 1]; }
    const float inv = 1.f / 819200.f;
    float mean = s * inv;
    float var = s2 * inv - mean * mean;
    float sc = g[ch] * rsqrtf(var + 1e-5f);
    sb[ch] = sc;
    sb[32 + ch] = bb[ch] - mean * sc;
  }
}

// ---------------- stats of a = W1*h without materializing a ----------------
template <typename TH>
__global__ __launch_bounds__(256) void stats1x1_part_k(const TH* __restrict__ H,
                                                       const float* __restrict__ w1,
                                                       float* __restrict__ part) {
  int t = blockIdx.x * 256 + threadIdx.x;        // 400*256 = 102400
  float sa[32], s2[32];
#pragma unroll
  for (int i = 0; i < 32; i++) { sa[i] = 0.f; s2[i] = 0.f; }
#pragma unroll 1
  for (int j = 0; j < 8; j++) {
    int n = t + j * 102400;                       // [0, 819200)
    int b = n / PIX, p = n - b * PIX;
    size_t base = (size_t)b * CHW + p;
    float h[32];
#pragma unroll
    for (int ci = 0; ci < 32; ci++) h[ci] = ldH(H, base + (size_t)ci * PIX);
#pragma unroll
    for (int co = 0; co < 32; co++) {
      float a = 0.f;
#pragma unroll
      for (int ci = 0; ci < 32; ci++) a = fmaf(h[ci], w1[co * 32 + ci], a);
      sa[co] += a; s2[co] += a * a;
    }
  }
  __shared__ float acc[4 * 64];
  int lane = threadIdx.x & 63, wv = threadIdx.x >> 6;
#pragma unroll
  for (int i = 0; i < 32; i++) {
    float a = sa[i], b = s2[i];
#pragma unroll
    for (int off = 32; off > 0; off >>= 1) { a += __shfl_down(a, off); b += __shfl_down(b, off); }
    if (lane == 0) { acc[wv * 64 + i] = a; acc[wv * 64 + 32 + i] = b; }
  }
  __syncthreads();
  if (threadIdx.x < 64) {
    float s = acc[threadIdx.x] + acc[64 + threadIdx.x] + acc[128 + threadIdx.x] + acc[192 + threadIdx.x];
    part[(size_t)blockIdx.x * 64 + threadIdx.x] = s;
  }
}

__global__ __launch_bounds__(64) void stats1x1_fin_k(const float* __restrict__ part,
                                                     const float* __restrict__ g,
                                                     const float* __restrict__ bb,
                                                     float* __restrict__ sb) {
  int co = threadIdx.x;
  if (co < 32) {
    float s = 0.f, s2 = 0.f;
    for (int j = 0; j < 400; j++) { s += part[j * 64 + co]; s2 += part[j * 64 + 32 + co]; }
    const float inv = 1.f / 819200.f;
    float mean = s * inv;
    float var = s2 * inv - mean * mean;
    float sc = g[co] * rsqrtf(var + 1e-5f);
    sb[co] = sc;
    sb[32 + co] = bb[co] - mean * sc;
  }
}

// ---------------- fused: H = relu(bn(X) [+ H]) ----------------
template <typename TH, bool RES>
__global__ __launch_bounds__(256) void fuse_k(const float* __restrict__ X,
                                              TH* __restrict__ H,
                                              const float* __restrict__ sb) {
  int idx = blockIdx.x * 256 + threadIdx.x;      // 819200
  int b = idx / PIX, p = idx - b * PIX;
  size_t base = (size_t)b * CHW + p;
#pragma unroll
  for (int ci = 0; ci < 32; ci++) {
    float v = X[base + (size_t)ci * PIX];
    v = fmaf(v, sb[ci], sb[32 + ci]);
    if (RES) v += ldH(H, base + (size_t)ci * PIX);
    v = fmaxf(v, 0.f);
    stH(H, base + (size_t)ci * PIX, v);
  }
}

// ---------------- conv3x3 32->32 p1 with inline o1 = relu(bn1(W1*h)) ----------------
// Restructured: 4 chunks of 8 o1-channels; 2 barriers per chunk + 1 staging barrier.
// All weight/scale indices are wave-uniform -> scalar loads (s_load), so the
// FMA loops are pure VALU with acc in VGPRs.
template <typename TH>
__global__ __launch_bounds__(256) void conv3_k(const TH* __restrict__ H,
                                               const float* __restrict__ w1,
                                               const float* __restrict__ sba,
                                               const float* __restrict__ w3,
                                               float* __restrict__ X) {
  __shared__ float hs[32 * 324];
  __shared__ float o1c[8 * 324];
  int tx = threadIdx.x & 15, ty = threadIdx.x >> 4;
  int tile_id = blockIdx.x;                       // 25 tiles (5x5 of 16x16)
  int ty0 = (tile_id / 5) * 16, tx0 = (tile_id % 5) * 16;
  int b = blockIdx.y;
  size_t ibase = (size_t)b * CHW;
  // stage full 32ch x 18x18 h halo
  for (int i = threadIdx.x; i < 32 * 324; i += 256) {
    int cj = i / 324, px = i - cj * 324;
    int iy = px / 18, ix = px - iy * 18;
    int gy = ty0 - 1 + iy, gx = tx0 - 1 + ix;
    float v = 0.f;
    if (gy >= 0 && gy < HW_ && gx >= 0 && gx < HW_)
      v = ldH(H, ibase + (size_t)cj * PIX + gy * HW_ + gx);
    hs[i] = v;
  }
  float acc[32];
#pragma unroll
  for (int i = 0; i < 32; i++) acc[i] = 0.f;
  __syncthreads();

#pragma unroll 1
  for (int chunk = 0; chunk < 4; chunk++) {
    // o1 for cm = chunk*8 .. chunk*8+7, whole halo tile.
    // (zero-padding applies AFTER bn+relu -> out-of-image halo is exactly 0)
    for (int px = threadIdx.x; px < 324; px += 256) {
      int iy = px / 18, ix = px - iy * 18;
      int gy = ty0 - 1 + iy, gx = tx0 - 1 + ix;
      bool inimg = (gy >= 0 && gy < HW_ && gx >= 0 && gx < HW_);
      float a[8];
#pragma unroll
      for (int u = 0; u < 8; u++) a[u] = 0.f;
#pragma unroll
      for (int cj = 0; cj < 32; cj++) {
        float hv = hs[cj * 324 + px];
#pragma unroll
        for (int u = 0; u < 8; u++)
          a[u] = fmaf(hv, w1[(chunk * 8 + u) * 32 + cj], a[u]);
      }
#pragma unroll
      for (int u = 0; u < 8; u++) {
        int cm = chunk * 8 + u;
        float o = inimg ? fmaxf(fmaf(a[u], sba[cm], sba[32 + cm]), 0.f) : 0.f;
        o1c[u * 324 + px] = o;
      }
    }
    __syncthreads();
#pragma unroll
    for (int u = 0; u < 8; u++) {
      int cm = chunk * 8 + u;
      float patch[9];
#pragma unroll
      for (int t = 0; t < 9; t++)
        patch[t] = o1c[u * 324 + (ty + t / 3) * 18 + tx + (t % 3)];
#pragma unroll
      for (int co = 0; co < 32; co++) {
        const float* wp = w3 + (co * 32 + cm) * 9;
        float a2 = acc[co];
#pragma unroll
        for (int t = 0; t < 9; t++) a2 = fmaf(patch[t], wp[t], a2);
        acc[co] = a2;
      }
    }
    __syncthreads();
  }
  int oy = ty0 + ty, ox = tx0 + tx;
#pragma unroll
  for (int co = 0; co < 32; co++) X[ibase + (size_t)co * PIX + oy * HW_ + ox] = acc[co];
}

// ---------------- pcaps weight transpose ----------------
__global__ __launch_bounds__(256) void wtrans_k(const float* __restrict__ w,
                                                float* __restrict__ wT) {
  int idx = blockIdx.x * 256 + threadIdx.x;      // 331776
  int co = idx / 2592, tap = idx - co * 2592;
  wT[tap * 128 + co] = w[idx];
}

// ---------------- primary caps: 32->128, k9 s8, + bias -> P[b][prim][8] ----------------
template <typename TH>
__global__ __launch_bounds__(128) void pcaps_k(const TH* __restrict__ Hh,
                                               const float* __restrict__ wT,
                                               const float* __restrict__ bias,
                                               float* __restrict__ P) {
  int oy = blockIdx.x, b = blockIdx.y;
  int co = threadIdx.x;
  float bv = bias[co];
  float acc[9];
#pragma unroll
  for (int j = 0; j < 9; j++) acc[j] = bv;
  size_t ibase = (size_t)b * CHW;
#pragma unroll 1
  for (int ci = 0; ci < 32; ci++) {
#pragma unroll 1
    for (int ky = 0; ky < 9; ky++) {
      size_t irow = ibase + (size_t)ci * PIX + (oy * 8 + ky) * HW_;
      const float* wr = wT + (ci * 81 + ky * 9) * 128 + co;
#pragma unroll
      for (int kx = 0; kx < 9; kx++) {
        float wv = wr[kx * 128];
#pragma unroll
        for (int ox = 0; ox < 9; ox++) acc[ox] = fmaf(ldH(Hh, irow + ox * 8 + kx), wv, acc[ox]);
      }
    }
  }
  int ch = co >> 3, k = co & 7;
#pragma unroll
  for (int ox = 0; ox < 9; ox++) {
    int pp = ch * 81 + oy * 9 + ox;
    P[((size_t)b * NPRIM + pp) * 8 + k] = acc[ox];
  }
}

// ---------------- u_hat[b][p][cd] = sum_k W[p][cd][k] * P[b][p][k] ----------------
__global__ __launch_bounds__(256) void uhat_k(const float* __restrict__ Pp,
                                              const float* __restrict__ W,
                                              float* __restrict__ UH) {
  int p = blockIdx.x;                             // 1296
  __shared__ __align__(16) float ush[1024];       // [128 b][8 k]
  for (int i = threadIdx.x; i < 1024; i += 256) {
    int b = i >> 3, k = i & 7;
    ush[i] = Pp[((size_t)b * NPRIM + p) * 8 + k];
  }
  int cdq = threadIdx.x & 31, bg = threadIdx.x >> 5;
  float4 w0[5], w1[5];
#pragma unroll
  for (int j = 0; j < 5; j++) {
    const float4* wp = (const float4*)(W + ((size_t)p * 160 + j * 32 + cdq) * 8);
    w0[j] = wp[0]; w1[j] = wp[1];
  }
  __syncthreads();
#pragma unroll 1
  for (int pass = 0; pass < 16; pass++) {
    int b = pass * 8 + bg;
    const float4* up = (const float4*)(ush + b * 8);
    float4 u0 = up[0], u1 = up[1];
#pragma unroll
    for (int j = 0; j < 5; j++) {
      float a = w0[j].x * u0.x + w0[j].y * u0.y + w0[j].z * u0.z + w0[j].w * u0.w +
                w1[j].x * u1.x + w1[j].y * u1.y + w1[j].z * u1.z + w1[j].w * u1.w;
      UH[((size_t)b * NPRIM + p) * 160 + j * 32 + cdq] = a;
    }
  }
}

// ---------------- s[b][c][d] = sum_p coeff * u_hat ----------------
template <bool UNIFORM>
__global__ __launch_bounds__(256) void sred_k(const float* __restrict__ UH,
                                              const float* __restrict__ blog,
                                              float* __restrict__ S) {
  int c = blockIdx.x, b = blockIdx.y;
  int d = threadIdx.x & 15, pg = threadIdx.x >> 4;
  float acc = 0.f;
  for (int p = pg; p < NPRIM; p += 16) {
    float cc;
    if (UNIFORM) {
      cc = 0.1f;
    } else {
      const float* br = blog + ((size_t)b * NPRIM + p) * 10;
      float bl[10];
      float mx = -3.4e38f;
#pragma unroll
      for (int j = 0; j < 10; j++) { bl[j] = br[j]; mx = fmaxf(mx, bl[j]); }
      float sum = 0.f, num = 0.f;
#pragma unroll
      for (int j = 0; j < 10; j++) {
        float e = __expf(bl[j] - mx);
        sum += e;
        if (j == c) num = e;
      }
      cc = num / sum;
    }
    acc += cc * UH[((size_t)b * NPRIM + p) * 160 + c * 16 + d];
  }
  __shared__ float red[256];
  red[threadIdx.x] = acc;
  __syncthreads();
  for (int st = 128; st >= 16; st >>= 1) {
    if (threadIdx.x < st) red[threadIdx.x] += red[threadIdx.x + st];
    __syncthreads();
  }
  if (threadIdx.x < 16) S[((size_t)b * 10 + c) * 16 + threadIdx.x] = red[threadIdx.x];
}

// ---------------- blog[b][p][c] (=|+=) sum_d u_hat * v ----------------
template <bool FIRST>
__global__ __launch_bounds__(256) void agr_k(const float* __restrict__ UH,
                                             const float* __restrict__ V,
                                             float* __restrict__ blog) {
  int idx = blockIdx.x * 256 + threadIdx.x;      // 1,658,880
  int c = idx % 10;
  int bp = idx / 10;
  int b = bp / NPRIM;
  const float* uh = UH + (size_t)bp * 160 + c * 16;
  const float* vv = V + ((size_t)b * 10 + c) * 16;
  float a = 0.f;
#pragma unroll
  for (int d = 0; d < 16; d++) a = fmaf(uh[d], vv[d], a);
  blog[idx] = FIRST ? a : (blog[idx] + a);
}

// ---------------- squash ----------------
template <bool FINAL>
__global__ __launch_bounds__(256) void squash_k(const float* __restrict__ S,
                                                float* __restrict__ V,
                                                float* __restrict__ out) {
  int idx = blockIdx.x * 256 + threadIdx.x;      // 1280
  if (idx >= 1280) return;
  const float* s = S + (size_t)idx * 16;
  float v[16];
  float n2 = 0.f;
#pragma unroll
  for (int d = 0; d < 16; d++) { v[d] = s[d]; n2 += v[d] * v[d]; }
  float sc = (n2 / (1.f + n2)) / sqrtf(n2 + 1e-9f);
  if (FINAL) {
#pragma unroll
    for (int d = 0; d < 16; d++) out[(size_t)idx * 16 + d] = v[d] * sc;
    out[20480 + idx] = sqrtf(n2 * sc * sc + 1e-9f);
  } else {
#pragma unroll
    for (int d = 0; d < 16; d++) V[(size_t)idx * 16 + d] = v[d] * sc;
  }
}

// ---------------- host-side orchestration ----------------
template <typename TH>
static void run_all(void* const* d_in, float* ws, float* out, size_t tail0, hipStream_t stream) {
  const float* x        = (const float*)d_in[0];
  const float* conv1_w  = (const float*)d_in[1];
  const float* conv1_b  = (const float*)d_in[2];
  const float* bn1_g    = (const float*)d_in[3];
  const float* bn1_b    = (const float*)d_in[4];
  const float* rb_c1_w  = (const float*)d_in[5];
  const float* rb_bn1_g = (const float*)d_in[6];
  const float* rb_bn1_b = (const float*)d_in[7];
  const float* rb_c2_w  = (const float*)d_in[8];
  const float* rb_bn2_g = (const float*)d_in[9];
  const float* rb_bn2_b = (const float*)d_in[10];
  const float* pcaps_w  = (const float*)d_in[11];
  const float* pcaps_b  = (const float*)d_in[12];
  const float* W_caps   = (const float*)d_in[13];

  float* X    = ws;
  TH*    H    = (TH*)(ws + 26214400);
  float* WT   = ws + tail0;
  float* PART = WT + 331776;
  float* SB   = PART + 32768;     // 8 sets x 64
  float* P    = SB + 512;
  float* BLOG = P + 1327104;
  float* S    = BLOG + 1658880;
  float* V    = S + 20480;
  float* UH   = ws;               // overlays dead X

  auto STATS = [&](const float* src, int set, const float* g_, const float* b_) {
    stats_part_k<<<dim3(25, 32), 256, 0, stream>>>(src, PART);
    stats_fin_k<<<1, 64, 0, stream>>>(PART, g_, b_, SB + set * 64);
  };

  wtrans_k<<<1296, 256, 0, stream>>>(pcaps_w, WT);
  conv1_k<<<3200, 256, 0, stream>>>(x, conv1_w, conv1_b, X);
  STATS(X, 0, bn1_g, bn1_b);
  fuse_k<TH, false><<<3200, 256, 0, stream>>>(X, H, SB + 0);

  for (int i = 0; i < 3; i++) {
    int sa = 1 + 2 * i, sx = 2 + 2 * i;
    stats1x1_part_k<TH><<<400, 256, 0, stream>>>(H, rb_c1_w + i * 1024, PART);
    stats1x1_fin_k<<<1, 64, 0, stream>>>(PART, rb_bn1_g + i * 32, rb_bn1_b + i * 32, SB + sa * 64);
    conv3_k<TH><<<dim3(25, 128), 256, 0, stream>>>(H, rb_c1_w + i * 1024, SB + sa * 64,
                                                   rb_c2_w + i * 9216, X);
    STATS(X, sx, rb_bn2_g + i * 32, rb_bn2_b + i * 32);
    fuse_k<TH, true><<<3200, 256, 0, stream>>>(X, H, SB + sx * 64);
  }

  pcaps_k<TH><<<dim3(9, 128), 128, 0, stream>>>(H, WT, pcaps_b, P);
  uhat_k<<<1296, 256, 0, stream>>>(P, W_caps, UH);

  sred_k<true><<<dim3(10, 128), 256, 0, stream>>>(UH, nullptr, S);
  squash_k<false><<<5, 256, 0, stream>>>(S, V, nullptr);
  agr_k<true><<<6480, 256, 0, stream>>>(UH, V, BLOG);
  sred_k<false><<<dim3(10, 128), 256, 0, stream>>>(UH, BLOG, S);
  squash_k<false><<<5, 256, 0, stream>>>(S, V, nullptr);
  agr_k<false><<<6480, 256, 0, stream>>>(UH, V, BLOG);
  sred_k<false><<<dim3(10, 128), 256, 0, stream>>>(UH, BLOG, S);
  squash_k<true><<<5, 256, 0, stream>>>(S, V, out);
}

extern "C" void kernel_launch(void* const* d_in, const int* in_sizes, int n_in,
                              void* d_out, int out_size, void* d_ws, size_t ws_size,
                              hipStream_t stream) {
  (void)in_sizes; (void)n_in; (void)out_size;
  float* ws = (float*)d_ws;
  float* out = (float*)d_out;
  // fp32-H layout needs (52,428,800 + 3,392,000)*4 = 223,283,200 bytes
  if (ws_size >= 223283200ull) {
    run_all<float>(d_in, ws, out, 52428800, stream);
  } else {
    // bf16-H layout needs (39,321,600 + 3,392,000)*4 = 170,854,400 bytes
    run_all<unsigned short>(d_in, ws, out, 39321600, stream);
  }
}

// Round 4
// 1776.838 us; speedup vs baseline: 2.5866x; 2.5866x over previous
//
#include <hip/hip_runtime.h>
#include <hip/hip_bf16.h>
#include <cstddef>

// ResCapsNet forward, round 4.
// conv3_k redesigned after r3 regression (VGPR 168 -> occ 11.5%):
//   phase 1: o1 = relu(bn1(w1*h)) per halo pixel, h read from global, a[32] regs,
//            w1T [ci][co] wide s_loads, result -> LDS as bf16 (20.7 KB total LDS)
//   ONE barrier
//   phase 2: acc[32] + patch[9], w3T [ci][co][t] contiguous per-ci wide s_loads.
// Phases don't overlap register lifetimes -> VGPR ~90, 16 waves/CU.
//
// ws layout (fp32-H mode, needs 223,283,200 B; bf16-H fallback if smaller):
//   X @ 0 (26,214,400 fl) | H @ 26,214,400 (26,214,400 fl) | tail:
//   WT 331,776 | PART 32,768 | SB 512 | P 1,327,104 | BLOG 1,658,880 | S 20,480 | V 20,480
//   W1T/W3T (1024 + 9216 fl) overlay P during the trunk (P only used post-trunk).

#define B_ 128
#define HW_ 80
#define PIX 6400
#define CHW 204800
#define NPRIM 1296

// ---- H storage helpers (fp32 or bf16) ----
__device__ inline float ldH(const float* p, size_t i) { return p[i]; }
__device__ inline float ldH(const unsigned short* p, size_t i) {
  union { unsigned int u; float f; } c; c.u = ((unsigned int)p[i]) << 16; return c.f;
}
__device__ inline void stH(float* p, size_t i, float v) { p[i] = v; }
__device__ inline void stH(unsigned short* p, size_t i, float v) {
  __hip_bfloat16 b = __float2bfloat16(v);
  p[i] = *reinterpret_cast<unsigned short*>(&b);
}
__device__ inline float bf16tof(unsigned short u) {
  union { unsigned int uu; float f; } c; c.uu = ((unsigned int)u) << 16; return c.f;
}
__device__ inline unsigned short ftobf16(float v) {
  __hip_bfloat16 b = __float2bfloat16(v);
  return *reinterpret_cast<unsigned short*>(&b);
}

// ---------------- conv1: 1->32, k3 s1 p1, + bias -> X raw ----------------
__global__ __launch_bounds__(256) void conv1_k(const float* __restrict__ x,
                                               const float* __restrict__ w,
                                               const float* __restrict__ bias,
                                               float* __restrict__ out) {
  int idx = blockIdx.x * 256 + threadIdx.x;      // 819200
  int b = idx / PIX, p = idx - b * PIX;
  int y = p / HW_, xx = p - y * HW_;
  const float* xb = x + (size_t)b * PIX;
  float in[3][3];
#pragma unroll
  for (int dy = 0; dy < 3; dy++) {
    int yy = y + dy - 1;
#pragma unroll
    for (int dx = 0; dx < 3; dx++) {
      int xc = xx + dx - 1;
      in[dy][dx] = (yy >= 0 && yy < HW_ && xc >= 0 && xc < HW_) ? xb[yy * HW_ + xc] : 0.f;
    }
  }
  size_t obase = (size_t)b * CHW + p;
#pragma unroll 1
  for (int co = 0; co < 32; co++) {
    float a = bias[co];
#pragma unroll
    for (int t = 0; t < 9; t++) a = fmaf(in[t / 3][t % 3], w[co * 9 + t], a);
    out[obase + (size_t)co * PIX] = a;
  }
}

// ---------------- BN stats over fp32 X ----------------
__global__ __launch_bounds__(256) void stats_part_k(const float* __restrict__ src,
                                                    float* __restrict__ part) {
  int ch = blockIdx.y;
  int p = blockIdx.x * 256 + threadIdx.x;        // 25*256 = 6400
  const float* sp = src + (size_t)ch * PIX + p;
  float s = 0.f, s2 = 0.f;
#pragma unroll 4
  for (int b = 0; b < B_; b++) {
    float v = sp[(size_t)b * CHW];
    s += v; s2 += v * v;
  }
  __shared__ float r1[256], r2[256];
  r1[threadIdx.x] = s; r2[threadIdx.x] = s2;
  __syncthreads();
  for (int st = 128; st > 0; st >>= 1) {
    if (threadIdx.x < st) { r1[threadIdx.x] += r1[threadIdx.x + st]; r2[threadIdx.x] += r2[threadIdx.x + st]; }
    __syncthreads();
  }
  if (threadIdx.x == 0) {
    part[ch * 50 + blockIdx.x * 2 + 0] = r1[0];
    part[ch * 50 + blockIdx.x * 2 + 1] = r2[0];
  }
}

__global__ __launch_bounds__(64) void stats_fin_k(const float* __restrict__ part,
                                                  const float* __restrict__ g,
                                                  const float* __restrict__ bb,
                                                  float* __restrict__ sb) {
  int ch = threadIdx.x;
  if (ch < 32) {
    float s = 0.f, s2 = 0.f;
    for (int j = 0; j < 25; j++) { s += part[ch * 50 + j * 2]; s2 += part[ch * 50 + j * 2 + 1]; }
    const float inv = 1.f / 819200.f;
    float mean = s * inv;
    float var = s2 * inv - mean * mean;
    float sc = g[ch] * rsqrtf(var + 1e-5f);
    sb[ch] = sc;
    sb[32 + ch] = bb[ch] - mean * sc;
  }
}

// ---------------- stats of a = W1*h without materializing a ----------------
template <typename TH>
__global__ __launch_bounds__(256) void stats1x1_part_k(const TH* __restrict__ H,
                                                       const float* __restrict__ w1,
                                                       float* __restrict__ part) {
  int t = blockIdx.x * 256 + threadIdx.x;        // 400*256 = 102400
  float sa[32], s2[32];
#pragma unroll
  for (int i = 0; i < 32; i++) { sa[i] = 0.f; s2[i] = 0.f; }
#pragma unroll 1
  for (int j = 0; j < 8; j++) {
    int n = t + j * 102400;                       // [0, 819200)
    int b = n / PIX, p = n - b * PIX;
    size_t base = (size_t)b * CHW + p;
    float h[32];
#pragma unroll
    for (int ci = 0; ci < 32; ci++) h[ci] = ldH(H, base + (size_t)ci * PIX);
#pragma unroll
    for (int co = 0; co < 32; co++) {
      float a = 0.f;
#pragma unroll
      for (int ci = 0; ci < 32; ci++) a = fmaf(h[ci], w1[co * 32 + ci], a);
      sa[co] += a; s2[co] += a * a;
    }
  }
  __shared__ float acc[4 * 64];
  int lane = threadIdx.x & 63, wv = threadIdx.x >> 6;
#pragma unroll
  for (int i = 0; i < 32; i++) {
    float a = sa[i], b = s2[i];
#pragma unroll
    for (int off = 32; off > 0; off >>= 1) { a += __shfl_down(a, off); b += __shfl_down(b, off); }
    if (lane == 0) { acc[wv * 64 + i] = a; acc[wv * 64 + 32 + i] = b; }
  }
  __syncthreads();
  if (threadIdx.x < 64) {
    float s = acc[threadIdx.x] + acc[64 + threadIdx.x] + acc[128 + threadIdx.x] + acc[192 + threadIdx.x];
    part[(size_t)blockIdx.x * 64 + threadIdx.x] = s;
  }
}

__global__ __launch_bounds__(64) void stats1x1_fin_k(const float* __restrict__ part,
                                                     const float* __restrict__ g,
                                                     const float* __restrict__ bb,
                                                     float* __restrict__ sb) {
  int co = threadIdx.x;
  if (co < 32) {
    float s = 0.f, s2 = 0.f;
    for (int j = 0; j < 400; j++) { s += part[j * 64 + co]; s2 += part[j * 64 + 32 + co]; }
    const float inv = 1.f / 819200.f;
    float mean = s * inv;
    float var = s2 * inv - mean * mean;
    float sc = g[co] * rsqrtf(var + 1e-5f);
    sb[co] = sc;
    sb[32 + co] = bb[co] - mean * sc;
  }
}

// ---------------- fused: H = relu(bn(X) [+ H]) ----------------
template <typename TH, bool RES>
__global__ __launch_bounds__(256) void fuse_k(const float* __restrict__ X,
                                              TH* __restrict__ H,
                                              const float* __restrict__ sb) {
  int idx = blockIdx.x * 256 + threadIdx.x;      // 819200
  int b = idx / PIX, p = idx - b * PIX;
  size_t base = (size_t)b * CHW + p;
#pragma unroll
  for (int ci = 0; ci < 32; ci++) {
    float v = X[base + (size_t)ci * PIX];
    v = fmaf(v, sb[ci], sb[32 + ci]);
    if (RES) v += ldH(H, base + (size_t)ci * PIX);
    v = fmaxf(v, 0.f);
    stH(H, base + (size_t)ci * PIX, v);
  }
}

// ---------------- per-res-block weight transposes ----------------
// w1T[ci][co] = w1[co][ci]; w3T[ci*288 + co*9 + t] = w3[(co*32+ci)*9 + t]
__global__ __launch_bounds__(256) void rbtrans_k(const float* __restrict__ w1,
                                                 const float* __restrict__ w3,
                                                 float* __restrict__ w1T,
                                                 float* __restrict__ w3T) {
  int idx = blockIdx.x * 256 + threadIdx.x;      // 10240
  if (idx < 1024) {
    int co = idx >> 5, ci = idx & 31;
    w1T[ci * 32 + co] = w1[co * 32 + ci];
  } else if (idx < 10240) {
    int j = idx - 1024;                           // 9216
    int co = j / 288, r = j - co * 288;
    int ci = r / 9, t = r - ci * 9;
    w3T[ci * 288 + co * 9 + t] = w3[(co * 32 + ci) * 9 + t];
  }
}

// ---------------- conv3x3 32->32 p1 with inline o1 = relu(bn1(w1*h)) ----------------
// Phase 1 (a[32] live, acc NOT yet live): o1 for all 32 ch per halo pixel,
// h from global, -> LDS bf16. One barrier. Phase 2 (acc[32] live): 3x3 conv.
template <typename TH>
__global__ __launch_bounds__(256) void conv3_k(const TH* __restrict__ H,
                                               const float* __restrict__ w1T,
                                               const float* __restrict__ sba,
                                               const float* __restrict__ w3T,
                                               float* __restrict__ X) {
  __shared__ unsigned short o1s[32 * 324];        // [ch][px], bf16, 20736 B
  int tile_id = blockIdx.x;                       // 25 tiles (5x5 of 16x16)
  int ty0 = (tile_id / 5) * 16, tx0 = (tile_id % 5) * 16;
  int b = blockIdx.y;
  size_t ibase = (size_t)b * CHW;

  for (int px = threadIdx.x; px < 324; px += 256) {
    int iy = px / 18, ix = px - iy * 18;
    int gy = ty0 - 1 + iy, gx = tx0 - 1 + ix;
    bool inimg = (gy >= 0 && gy < HW_ && gx >= 0 && gx < HW_);
    float a[32];
#pragma unroll
    for (int u = 0; u < 32; u++) a[u] = 0.f;
    if (inimg) {
      size_t hoff = ibase + (size_t)gy * HW_ + gx;
#pragma unroll 4
      for (int cj = 0; cj < 32; cj++) {
        float hv = ldH(H, hoff + (size_t)cj * PIX);
        const float* wr = w1T + cj * 32;
#pragma unroll
        for (int u = 0; u < 32; u++) a[u] = fmaf(hv, wr[u], a[u]);
      }
    }
#pragma unroll
    for (int u = 0; u < 32; u++) {
      // zero-padding applies AFTER bn+relu: out-of-image halo is exactly 0
      float o = inimg ? fmaxf(fmaf(a[u], sba[u], sba[32 + u]), 0.f) : 0.f;
      o1s[u * 324 + px] = ftobf16(o);
    }
  }
  __syncthreads();

  int tx = threadIdx.x & 15, ty = threadIdx.x >> 4;
  float acc[32];
#pragma unroll
  for (int i = 0; i < 32; i++) acc[i] = 0.f;
#pragma unroll 1
  for (int ci = 0; ci < 32; ci++) {
    float patch[9];
#pragma unroll
    for (int t = 0; t < 9; t++)
      patch[t] = bf16tof(o1s[ci * 324 + (ty + t / 3) * 18 + tx + (t % 3)]);
    const float* wp = w3T + ci * 288;              // contiguous 288 fl -> wide s_loads
#pragma unroll
    for (int co = 0; co < 32; co++) {
      float a2 = acc[co];
#pragma unroll
      for (int t = 0; t < 9; t++) a2 = fmaf(patch[t], wp[co * 9 + t], a2);
      acc[co] = a2;
    }
  }
  int oy = ty0 + ty, ox = tx0 + tx;
#pragma unroll
  for (int co = 0; co < 32; co++) X[ibase + (size_t)co * PIX + oy * HW_ + ox] = acc[co];
}

// ---------------- pcaps weight transpose ----------------
__global__ __launch_bounds__(256) void wtrans_k(const float* __restrict__ w,
                                                float* __restrict__ wT) {
  int idx = blockIdx.x * 256 + threadIdx.x;      // 331776
  int co = idx / 2592, tap = idx - co * 2592;
  wT[tap * 128 + co] = w[idx];
}

// ---------------- primary caps: 32->128, k9 s8, + bias -> P[b][prim][8] ----------------
template <typename TH>
__global__ __launch_bounds__(128) void pcaps_k(const TH* __restrict__ Hh,
                                               const float* __restrict__ wT,
                                               const float* __restrict__ bias,
                                               float* __restrict__ P) {
  int oy = blockIdx.x, b = blockIdx.y;
  int co = threadIdx.x;
  float bv = bias[co];
  float acc[9];
#pragma unroll
  for (int j = 0; j < 9; j++) acc[j] = bv;
  size_t ibase = (size_t)b * CHW;
#pragma unroll 1
  for (int ci = 0; ci < 32; ci++) {
#pragma unroll 1
    for (int ky = 0; ky < 9; ky++) {
      size_t irow = ibase + (size_t)ci * PIX + (oy * 8 + ky) * HW_;
      const float* wr = wT + (ci * 81 + ky * 9) * 128 + co;
#pragma unroll
      for (int kx = 0; kx < 9; kx++) {
        float wv = wr[kx * 128];
#pragma unroll
        for (int ox = 0; ox < 9; ox++) acc[ox] = fmaf(ldH(Hh, irow + ox * 8 + kx), wv, acc[ox]);
      }
    }
  }
  int ch = co >> 3, k = co & 7;
#pragma unroll
  for (int ox = 0; ox < 9; ox++) {
    int pp = ch * 81 + oy * 9 + ox;
    P[((size_t)b * NPRIM + pp) * 8 + k] = acc[ox];
  }
}

// ---------------- u_hat[b][p][cd] = sum_k W[p][cd][k] * P[b][p][k] ----------------
__global__ __launch_bounds__(256) void uhat_k(const float* __restrict__ Pp,
                                              const float* __restrict__ W,
                                              float* __restrict__ UH) {
  int p = blockIdx.x;                             // 1296
  __shared__ __align__(16) float ush[1024];       // [128 b][8 k]
  for (int i = threadIdx.x; i < 1024; i += 256) {
    int b = i >> 3, k = i & 7;
    ush[i] = Pp[((size_t)b * NPRIM + p) * 8 + k];
  }
  int cdq = threadIdx.x & 31, bg = threadIdx.x >> 5;
  float4 w0[5], w1[5];
#pragma unroll
  for (int j = 0; j < 5; j++) {
    const float4* wp = (const float4*)(W + ((size_t)p * 160 + j * 32 + cdq) * 8);
    w0[j] = wp[0]; w1[j] = wp[1];
  }
  __syncthreads();
#pragma unroll 1
  for (int pass = 0; pass < 16; pass++) {
    int b = pass * 8 + bg;
    const float4* up = (const float4*)(ush + b * 8);
    float4 u0 = up[0], u1 = up[1];
#pragma unroll
    for (int j = 0; j < 5; j++) {
      float a = w0[j].x * u0.x + w0[j].y * u0.y + w0[j].z * u0.z + w0[j].w * u0.w +
                w1[j].x * u1.x + w1[j].y * u1.y + w1[j].z * u1.z + w1[j].w * u1.w;
      UH[((size_t)b * NPRIM + p) * 160 + j * 32 + cdq] = a;
    }
  }
}

// ---------------- s[b][c][d] = sum_p coeff * u_hat ----------------
template <bool UNIFORM>
__global__ __launch_bounds__(256) void sred_k(const float* __restrict__ UH,
                                              const float* __restrict__ blog,
                                              float* __restrict__ S) {
  int c = blockIdx.x, b = blockIdx.y;
  int d = threadIdx.x & 15, pg = threadIdx.x >> 4;
  float acc = 0.f;
  for (int p = pg; p < NPRIM; p += 16) {
    float cc;
    if (UNIFORM) {
      cc = 0.1f;
    } else {
      const float* br = blog + ((size_t)b * NPRIM + p) * 10;
      float bl[10];
      float mx = -3.4e38f;
#pragma unroll
      for (int j = 0; j < 10; j++) { bl[j] = br[j]; mx = fmaxf(mx, bl[j]); }
      float sum = 0.f, num = 0.f;
#pragma unroll
      for (int j = 0; j < 10; j++) {
        float e = __expf(bl[j] - mx);
        sum += e;
        if (j == c) num = e;
      }
      cc = num / sum;
    }
    acc += cc * UH[((size_t)b * NPRIM + p) * 160 + c * 16 + d];
  }
  __shared__ float red[256];
  red[threadIdx.x] = acc;
  __syncthreads();
  for (int st = 128; st >= 16; st >>= 1) {
    if (threadIdx.x < st) red[threadIdx.x] += red[threadIdx.x + st];
    __syncthreads();
  }
  if (threadIdx.x < 16) S[((size_t)b * 10 + c) * 16 + threadIdx.x] = red[threadIdx.x];
}

// ---------------- blog[b][p][c] (=|+=) sum_d u_hat * v ----------------
template <bool FIRST>
__global__ __launch_bounds__(256) void agr_k(const float* __restrict__ UH,
                                             const float* __restrict__ V,
                                             float* __restrict__ blog) {
  int idx = blockIdx.x * 256 + threadIdx.x;      // 1,658,880
  int c = idx % 10;
  int bp = idx / 10;
  int b = bp / NPRIM;
  const float* uh = UH + (size_t)bp * 160 + c * 16;
  const float* vv = V + ((size_t)b * 10 + c) * 16;
  float a = 0.f;
#pragma unroll
  for (int d = 0; d < 16; d++) a = fmaf(uh[d], vv[d], a);
  blog[idx] = FIRST ? a : (blog[idx] + a);
}

// ---------------- squash ----------------
template <bool FINAL>
__global__ __launch_bounds__(256) void squash_k(const float* __restrict__ S,
                                                float* __restrict__ V,
                                                float* __restrict__ out) {
  int idx = blockIdx.x * 256 + threadIdx.x;      // 1280
  if (idx >= 1280) return;
  const float* s = S + (size_t)idx * 16;
  float v[16];
  float n2 = 0.f;
#pragma unroll
  for (int d = 0; d < 16; d++) { v[d] = s[d]; n2 += v[d] * v[d]; }
  float sc = (n2 / (1.f + n2)) / sqrtf(n2 + 1e-9f);
  if (FINAL) {
#pragma unroll
    for (int d = 0; d < 16; d++) out[(size_t)idx * 16 + d] = v[d] * sc;
    out[20480 + idx] = sqrtf(n2 * sc * sc + 1e-9f);
  } else {
#pragma unroll
    for (int d = 0; d < 16; d++) V[(size_t)idx * 16 + d] = v[d] * sc;
  }
}

// ---------------- host-side orchestration ----------------
template <typename TH>
static void run_all(void* const* d_in, float* ws, float* out, size_t tail0, hipStream_t stream) {
  const float* x        = (const float*)d_in[0];
  const float* conv1_w  = (const float*)d_in[1];
  const float* conv1_b  = (const float*)d_in[2];
  const float* bn1_g    = (const float*)d_in[3];
  const float* bn1_b    = (const float*)d_in[4];
  const float* rb_c1_w  = (const float*)d_in[5];
  const float* rb_bn1_g = (const float*)d_in[6];
  const float* rb_bn1_b = (const float*)d_in[7];
  const float* rb_c2_w  = (const float*)d_in[8];
  const float* rb_bn2_g = (const float*)d_in[9];
  const float* rb_bn2_b = (const float*)d_in[10];
  const float* pcaps_w  = (const float*)d_in[11];
  const float* pcaps_b  = (const float*)d_in[12];
  const float* W_caps   = (const float*)d_in[13];

  float* X    = ws;
  TH*    H    = (TH*)(ws + 26214400);
  float* WT   = ws + tail0;
  float* PART = WT + 331776;
  float* SB   = PART + 32768;     // 8 sets x 64
  float* P    = SB + 512;
  float* BLOG = P + 1327104;
  float* S    = BLOG + 1658880;
  float* V    = S + 20480;
  float* UH   = ws;               // overlays dead X
  // trunk-phase overlays (P is only used post-trunk)
  float* W1T  = P;                // 1024 fl
  float* W3T  = P + 1024;         // 9216 fl

  auto STATS = [&](const float* src, int set, const float* g_, const float* b_) {
    stats_part_k<<<dim3(25, 32), 256, 0, stream>>>(src, PART);
    stats_fin_k<<<1, 64, 0, stream>>>(PART, g_, b_, SB + set * 64);
  };

  wtrans_k<<<1296, 256, 0, stream>>>(pcaps_w, WT);
  conv1_k<<<3200, 256, 0, stream>>>(x, conv1_w, conv1_b, X);
  STATS(X, 0, bn1_g, bn1_b);
  fuse_k<TH, false><<<3200, 256, 0, stream>>>(X, H, SB + 0);

  for (int i = 0; i < 3; i++) {
    int sa = 1 + 2 * i, sx = 2 + 2 * i;
    stats1x1_part_k<TH><<<400, 256, 0, stream>>>(H, rb_c1_w + i * 1024, PART);
    stats1x1_fin_k<<<1, 64, 0, stream>>>(PART, rb_bn1_g + i * 32, rb_bn1_b + i * 32, SB + sa * 64);
    rbtrans_k<<<40, 256, 0, stream>>>(rb_c1_w + i * 1024, rb_c2_w + i * 9216, W1T, W3T);
    conv3_k<TH><<<dim3(25, 128), 256, 0, stream>>>(H, W1T, SB + sa * 64, W3T, X);
    STATS(X, sx, rb_bn2_g + i * 32, rb_bn2_b + i * 32);
    fuse_k<TH, true><<<3200, 256, 0, stream>>>(X, H, SB + sx * 64);
  }

  pcaps_k<TH><<<dim3(9, 128), 128, 0, stream>>>(H, WT, pcaps_b, P);
  uhat_k<<<1296, 256, 0, stream>>>(P, W_caps, UH);

  sred_k<true><<<dim3(10, 128), 256, 0, stream>>>(UH, nullptr, S);
  squash_k<false><<<5, 256, 0, stream>>>(S, V, nullptr);
  agr_k<true><<<6480, 256, 0, stream>>>(UH, V, BLOG);
  sred_k<false><<<dim3(10, 128), 256, 0, stream>>>(UH, BLOG, S);
  squash_k<false><<<5, 256, 0, stream>>>(S, V, nullptr);
  agr_k<false><<<6480, 256, 0, stream>>>(UH, V, BLOG);
  sred_k<false><<<dim3(10, 128), 256, 0, stream>>>(UH, BLOG, S);
  squash_k<true><<<5, 256, 0, stream>>>(S, V, out);
}

extern "C" void kernel_launch(void* const* d_in, const int* in_sizes, int n_in,
                              void* d_out, int out_size, void* d_ws, size_t ws_size,
                              hipStream_t stream) {
  (void)in_sizes; (void)n_in; (void)out_size;
  float* ws = (float*)d_ws;
  float* out = (float*)d_out;
  // fp32-H layout needs (52,428,800 + 3,392,000)*4 = 223,283,200 bytes
  if (ws_size >= 223283200ull) {
    run_all<float>(d_in, ws, out, 52428800, stream);
  } else {
    // bf16-H layout needs (39,321,600 + 3,392,000)*4 = 170,854,400 bytes
    run_all<unsigned short>(d_in, ws, out, 39321600, stream);
  }
}